// Round 1
// baseline (2754.162 us; speedup 1.0000x reference)
//
#include <hip/hip_runtime.h>

// ---------------------------------------------------------------------------
// RGCN 2-layer forward on MI355X. Round 0: correctness-first fp32 baseline.
//   N=50000, E=800000, IN=768, HID=OUT=128, R=8
// Pipeline:
//   counts[d*8+t] += 1                      (once, shared by both layers)
//   layer: h[r] = x @ W[r]  (GEMM)          (all r, or per-r if ws small)
//          agg[dst] += h[type][src]/count   (wave-per-edge scatter, atomics)
//          x' = (relu)(agg + x@root + b)    (GEMM with fused epilogue)
//   out[:, :768] = feature ; out[:, 768:] = layer2 result
// ---------------------------------------------------------------------------

#define IN_DIM 768
#define HID    128
#define NREL   8

constexpr int BM = 128;   // rows per block
constexpr int BN = 128;   // cols per block (= full output width)
constexpr int KT = 16;    // k-tile

// ---------------------------------------------------------------- GEMM ----
// C[., 0:128] (+rel offset) = A[M,K] @ B[K,128]  (+agg)(+bias)(relu)
template <bool RELU, bool HAS_AGG, bool HAS_BIAS>
__global__ __launch_bounds__(256) void rgcn_gemm(
    const float* __restrict__ A, int lda, int M, int K,
    const float* __restrict__ B, long bstride,
    const float* __restrict__ bias,
    const float* __restrict__ agg,
    float* __restrict__ C, long cstride, int ldc, int coff)
{
    __shared__ float As[KT][BM];   // transposed: As[k][row]
    __shared__ float Bs[KT][BN];

    const int tid = threadIdx.x;
    const int m0  = blockIdx.x * BM;
    const float* Bp = B + (long)blockIdx.y * bstride;
    float*       Cp = C + (long)blockIdx.y * cstride;

    const int tc = (tid & 15) << 3;  // col start within tile (0..120)
    const int tr = (tid >> 4) << 3;  // row start within tile (0..120)

    const int la_r = tid >> 2;        // 0..63
    const int la_k = (tid & 3) << 2;  // 0,4,8,12

    float acc[8][8];
#pragma unroll
    for (int i = 0; i < 8; ++i)
#pragma unroll
        for (int j = 0; j < 8; ++j) acc[i][j] = 0.f;

    for (int k0 = 0; k0 < K; k0 += KT) {
        // stage A (two 64-row halves), transposed into LDS
#pragma unroll
        for (int h = 0; h < 2; ++h) {
            const int rrow = la_r + h * 64;
            const int arow = m0 + rrow;
            float4 av = make_float4(0.f, 0.f, 0.f, 0.f);
            if (arow < M)
                av = *(const float4*)&A[(long)arow * lda + k0 + la_k];
            As[la_k + 0][rrow] = av.x;
            As[la_k + 1][rrow] = av.y;
            As[la_k + 2][rrow] = av.z;
            As[la_k + 3][rrow] = av.w;
        }
        // stage B (16 x 128)
#pragma unroll
        for (int h = 0; h < 2; ++h) {
            const int f  = tid + h * 256;
            const int kk = f >> 5;
            const int c4 = (f & 31) << 2;
            *(float4*)&Bs[kk][c4] =
                *(const float4*)&Bp[(long)(k0 + kk) * BN + c4];
        }
        __syncthreads();

#pragma unroll
        for (int kk = 0; kk < KT; ++kk) {
            const float4 a0 = *(const float4*)&As[kk][tr];
            const float4 a1 = *(const float4*)&As[kk][tr + 4];
            const float4 b0 = *(const float4*)&Bs[kk][tc];
            const float4 b1 = *(const float4*)&Bs[kk][tc + 4];
            const float a[8] = {a0.x, a0.y, a0.z, a0.w, a1.x, a1.y, a1.z, a1.w};
            const float b[8] = {b0.x, b0.y, b0.z, b0.w, b1.x, b1.y, b1.z, b1.w};
#pragma unroll
            for (int i = 0; i < 8; ++i)
#pragma unroll
                for (int j = 0; j < 8; ++j)
                    acc[i][j] = fmaf(a[i], b[j], acc[i][j]);
        }
        __syncthreads();
    }

    // epilogue
#pragma unroll
    for (int i = 0; i < 8; ++i) {
        const int row = m0 + tr + i;
        if (row < M) {
            float v[8];
#pragma unroll
            for (int j = 0; j < 8; ++j) v[j] = acc[i][j];
            if (HAS_AGG) {
                const float4 g0 = *(const float4*)&agg[(long)row * 128 + tc];
                const float4 g1 = *(const float4*)&agg[(long)row * 128 + tc + 4];
                v[0] += g0.x; v[1] += g0.y; v[2] += g0.z; v[3] += g0.w;
                v[4] += g1.x; v[5] += g1.y; v[6] += g1.z; v[7] += g1.w;
            }
            if (HAS_BIAS) {
                const float4 g0 = *(const float4*)&bias[tc];
                const float4 g1 = *(const float4*)&bias[tc + 4];
                v[0] += g0.x; v[1] += g0.y; v[2] += g0.z; v[3] += g0.w;
                v[4] += g1.x; v[5] += g1.y; v[6] += g1.z; v[7] += g1.w;
            }
            if (RELU) {
#pragma unroll
                for (int j = 0; j < 8; ++j) v[j] = fmaxf(v[j], 0.f);
            }
            float* cp = &Cp[(long)row * ldc + coff + tc];
            *(float4*)cp       = make_float4(v[0], v[1], v[2], v[3]);
            *(float4*)(cp + 4) = make_float4(v[4], v[5], v[6], v[7]);
        }
    }
}

// ------------------------------------------------------------- counts ----
__global__ __launch_bounds__(256) void rgcn_count(
    const int* __restrict__ edst, const int* __restrict__ etype, int E,
    float* __restrict__ counts)
{
    const int e = blockIdx.x * blockDim.x + threadIdx.x;
    if (e < E) atomicAdd(&counts[(long)edst[e] * NREL + etype[e]], 1.0f);
}

// ------------------------------------------------------------ scatter ----
// one wave (64 lanes) per edge; lane handles 2 channels (float2)
__global__ __launch_bounds__(256) void rgcn_scatter(
    const int* __restrict__ esrc, const int* __restrict__ edst,
    const int* __restrict__ etype, int E, int filter_rel, long h_rel_stride,
    const float* __restrict__ counts, const float* __restrict__ h,
    float* __restrict__ agg)
{
    const long gtid = (long)blockIdx.x * blockDim.x + threadIdx.x;
    const int  w    = (int)(gtid >> 6);
    if (w >= E) return;
    const int t = etype[w];
    if (filter_rel >= 0 && t != filter_rel) return;
    const int lane = threadIdx.x & 63;
    const int s    = esrc[w];
    const int d    = edst[w];
    const float norm = 1.0f / fmaxf(counts[(long)d * NREL + t], 1.0f);
    const float* hp = h +
        (filter_rel >= 0 ? 0L : (long)t * h_rel_stride) +
        (long)s * 128 + (lane << 1);
    const float2 v = *(const float2*)hp;
    float* ap = agg + (long)d * 128 + (lane << 1);
    atomicAdd(ap,     v.x * norm);
    atomicAdd(ap + 1, v.y * norm);
}

// --------------------------------------------------------- copy feature ---
__global__ __launch_bounds__(256) void rgcn_copy_feat(
    const float* __restrict__ f, float* __restrict__ out, int N)
{
    const int idx   = blockIdx.x * blockDim.x + threadIdx.x;
    const int total = N * (IN_DIM / 4);
    if (idx >= total) return;
    const int n  = idx / (IN_DIM / 4);
    const int k4 = (idx % (IN_DIM / 4)) << 2;
    *(float4*)&out[(long)n * (IN_DIM + 128) + k4] =
        *(const float4*)&f[(long)n * IN_DIM + k4];
}

// ------------------------------------------------------------- launch ----
extern "C" void kernel_launch(void* const* d_in, const int* in_sizes, int n_in,
                              void* d_out, int out_size, void* d_ws,
                              size_t ws_size, hipStream_t stream)
{
    const float* feature = (const float*)d_in[0];
    const int*   eidx    = (const int*)d_in[1];
    const int*   etype   = (const int*)d_in[2];
    const float* w1      = (const float*)d_in[3];
    const float* root1   = (const float*)d_in[4];
    const float* b1      = (const float*)d_in[5];
    const float* w2      = (const float*)d_in[6];
    const float* root2   = (const float*)d_in[7];
    const float* b2      = (const float*)d_in[8];

    const int N = in_sizes[0] / IN_DIM;  // 50000
    const int E = in_sizes[2];           // 800000
    const int* esrc = eidx;
    const int* edst = eidx + E;

    char* ws = (char*)d_ws;
    const size_t cnt_bytes = (size_t)N * NREL * 4;  // 1.6 MB
    const size_t mat_bytes = (size_t)N * 128 * 4;   // 25.6 MB
    float* counts = (float*)ws;
    float* agg    = (float*)(ws + cnt_bytes);
    float* x1     = (float*)(ws + cnt_bytes + mat_bytes);
    float* hbuf   = (float*)(ws + cnt_bytes + 2 * mat_bytes);
    const size_t base_bytes = cnt_bytes + 2 * mat_bytes;
    const bool full = ws_size >= base_bytes + (size_t)NREL * mat_bytes;

    const int gemm_gx    = (N + BM - 1) / BM;         // 391
    const int scat_blks  = (int)(((long)E * 64 + 255) / 256);
    const int count_blks = (E + 255) / 256;
    const int copy_blks  = (N * (IN_DIM / 4) + 255) / 256;

    // counts (shared by both layers)
    hipMemsetAsync(counts, 0, cnt_bytes, stream);
    rgcn_count<<<count_blks, 256, 0, stream>>>(edst, etype, E, counts);

    // ---------------- layer 1 ----------------
    hipMemsetAsync(agg, 0, mat_bytes, stream);
    if (full) {
        rgcn_gemm<false, false, false><<<dim3(gemm_gx, NREL), 256, 0, stream>>>(
            feature, IN_DIM, N, IN_DIM, w1, (long)IN_DIM * 128, nullptr,
            nullptr, hbuf, (long)N * 128, 128, 0);
        rgcn_scatter<<<scat_blks, 256, 0, stream>>>(
            esrc, edst, etype, E, -1, (long)N * 128, counts, hbuf, agg);
    } else {
        for (int r = 0; r < NREL; ++r) {
            rgcn_gemm<false, false, false><<<dim3(gemm_gx, 1), 256, 0, stream>>>(
                feature, IN_DIM, N, IN_DIM, w1 + (long)r * IN_DIM * 128, 0,
                nullptr, nullptr, hbuf, 0, 128, 0);
            rgcn_scatter<<<scat_blks, 256, 0, stream>>>(
                esrc, edst, etype, E, r, 0, counts, hbuf, agg);
        }
    }
    // x1 = relu(agg + feature @ root1 + b1)
    rgcn_gemm<true, true, true><<<dim3(gemm_gx, 1), 256, 0, stream>>>(
        feature, IN_DIM, N, IN_DIM, root1, 0, b1, agg, x1, 0, 128, 0);

    // ---------------- layer 2 ----------------
    hipMemsetAsync(agg, 0, mat_bytes, stream);
    if (full) {
        rgcn_gemm<false, false, false><<<dim3(gemm_gx, NREL), 256, 0, stream>>>(
            x1, 128, N, 128, w2, (long)128 * 128, nullptr, nullptr, hbuf,
            (long)N * 128, 128, 0);
        rgcn_scatter<<<scat_blks, 256, 0, stream>>>(
            esrc, edst, etype, E, -1, (long)N * 128, counts, hbuf, agg);
    } else {
        for (int r = 0; r < NREL; ++r) {
            rgcn_gemm<false, false, false><<<dim3(gemm_gx, 1), 256, 0, stream>>>(
                x1, 128, N, 128, w2 + (long)r * 128 * 128, 0, nullptr, nullptr,
                hbuf, 0, 128, 0);
            rgcn_scatter<<<scat_blks, 256, 0, stream>>>(
                esrc, edst, etype, E, r, 0, counts, hbuf, agg);
        }
    }
    // out[:, 768:896] = agg + x1 @ root2 + b2
    rgcn_gemm<false, true, true><<<dim3(gemm_gx, 1), 256, 0, stream>>>(
        x1, 128, N, 128, root2, 0, b2, agg, (float*)d_out, 0, IN_DIM + 128,
        IN_DIM);
    // out[:, 0:768] = feature
    rgcn_copy_feat<<<copy_blks, 256, 0, stream>>>(feature, (float*)d_out, N);
}

// Round 2
// 1657.006 us; speedup vs baseline: 1.6621x; 1.6621x over previous
//
#include <hip/hip_runtime.h>
#include <hip/hip_bf16.h>

// ---------------------------------------------------------------------------
// RGCN 2-layer forward, MI355X. Round 1: bf16 MFMA GEMMs (16x16x32), fp32
// atomic scatter. N=50000, E=800000, IN=768, HID=OUT=128, R=8.
// GEMM: 128x128 tile, BK=64, 4 waves, global_load_lds(16B) staging with
// XOR chunk-swizzle (pre-swizzled global source, swizzled ds_read_b128).
// ---------------------------------------------------------------------------

typedef __hip_bfloat16 bf16;
typedef __attribute__((ext_vector_type(4))) float f32x4;
typedef __attribute__((ext_vector_type(8))) short s16x8;

#define IN_DIM 768
#define NREL   8

__device__ __forceinline__ void gload16(const void* g, void* l) {
    __builtin_amdgcn_global_load_lds(
        (const __attribute__((address_space(1))) void*)g,
        (__attribute__((address_space(3))) void*)l, 16, 0, 0);
}

// C = A[M,K](bf16) @ BT[128,K]^T(bf16) (+agg+bias)(relu) -> OutT
// swz_nrel: 0 => grid.x = m-tiles (rel=0). else grid.x = nmt*swz_nrel with
// XCD-aware mapping so one m-tile's relations share an XCD L2.
template <bool RELU, bool AGGBIAS, bool GUARD, typename OutT>
__global__ __launch_bounds__(256) void mfma_gemm(
    const bf16* __restrict__ A, int lda,
    const bf16* __restrict__ BT, long brel,
    const float* __restrict__ agg, const float* __restrict__ bias,
    OutT* __restrict__ C, long crel, int ldc, int coff,
    int M, int K, int nmt, int swz_nrel)
{
    __shared__ bf16 Asm[128 * 64];
    __shared__ bf16 Bsm[128 * 64];

    const int tid  = threadIdx.x;
    const int lane = tid & 63;
    const int wrow = ((tid >> 7) & 1) * 64;
    const int wcol = ((tid >> 6) & 1) * 64;

    int mtile, rel;
    if (swz_nrel == 0) {
        mtile = blockIdx.x; rel = 0;
    } else {
        // per-XCD contiguous ranges: id%8 = xcd, id/8 = seq within xcd
        const int id  = blockIdx.x;
        const int tot = nmt * swz_nrel;     // assumed %8==0 (391*8=3128)
        const int per = tot >> 3;
        const int w   = (id & 7) * per + (id >> 3);
        rel   = w % swz_nrel;
        mtile = w / swz_nrel;
    }
    const long m0 = (long)mtile * 128;
    const bf16* Bp = BT + (long)rel * brel;

    f32x4 acc[4][4];
#pragma unroll
    for (int i = 0; i < 4; ++i)
#pragma unroll
        for (int j = 0; j < 4; ++j) acc[i][j] = (f32x4){0.f, 0.f, 0.f, 0.f};

    for (int k0 = 0; k0 < K; k0 += 64) {
        // stage A and BT tiles: [128 rows][8 chunks of 16B], chunk^=(row&7)
#pragma unroll
        for (int i = 0; i < 4; ++i) {
            const int flat = i * 256 + tid;
            const int row  = flat >> 3;
            const int sch  = (flat & 7) ^ (row & 7);  // unswizzled src chunk
            char* ldsA = (char*)Asm + (i * 256 + (tid & 192)) * 16;
            char* ldsB = (char*)Bsm + (i * 256 + (tid & 192)) * 16;
            gload16(A  + (m0 + row) * (long)lda + k0 + sch * 8, ldsA);
            gload16(Bp + (long)row * K          + k0 + sch * 8, ldsB);
        }
        __syncthreads();

#pragma unroll
        for (int ks = 0; ks < 2; ++ks) {
            s16x8 af[4], bfr[4];
            const int g = ks * 4 + (lane >> 4);  // global chunk 0..7
#pragma unroll
            for (int i = 0; i < 4; ++i) {
                const int ar = wrow + i * 16 + (lane & 15);
                af[i] = *(const s16x8*)((const char*)Asm + ar * 128 +
                                        (g ^ (ar & 7)) * 16);
                const int br = wcol + i * 16 + (lane & 15);
                bfr[i] = *(const s16x8*)((const char*)Bsm + br * 128 +
                                         (g ^ (br & 7)) * 16);
            }
#pragma unroll
            for (int i = 0; i < 4; ++i)
#pragma unroll
                for (int j = 0; j < 4; ++j)
                    acc[i][j] = __builtin_amdgcn_mfma_f32_16x16x32_bf16(
                        af[i], bfr[j], acc[i][j], 0, 0, 0);
        }
        __syncthreads();
    }

    // epilogue: C/D layout col=lane&15, row=(lane>>4)*4+reg (m89-verified)
    float breg[4];
    if (AGGBIAS) {
#pragma unroll
        for (int j = 0; j < 4; ++j) breg[j] = bias[wcol + j * 16 + (lane & 15)];
    }
    OutT* Cp = C + (long)rel * crel;
#pragma unroll
    for (int i = 0; i < 4; ++i) {
#pragma unroll
        for (int r = 0; r < 4; ++r) {
            const long row = m0 + wrow + i * 16 + (lane >> 4) * 4 + r;
            if (GUARD && row >= M) continue;
#pragma unroll
            for (int j = 0; j < 4; ++j) {
                float v = acc[i][j][r];
                const int col = wcol + j * 16 + (lane & 15);
                if (AGGBIAS) v += agg[row * 128 + col] + breg[j];
                if (RELU) v = fmaxf(v, 0.f);
                if constexpr (sizeof(OutT) == 2)
                    Cp[row * (long)ldc + coff + col] = __float2bfloat16(v);
                else
                    Cp[row * (long)ldc + coff + col] = v;
            }
        }
    }
}

// ------------------------------------------------------------- helpers ----
__global__ __launch_bounds__(256) void rgcn_count(
    const int* __restrict__ edst, const int* __restrict__ etype, int E,
    float* __restrict__ counts)
{
    const int e = blockIdx.x * blockDim.x + threadIdx.x;
    if (e < E) atomicAdd(&counts[(long)edst[e] * NREL + etype[e]], 1.0f);
}

// one wave per edge; lane handles 2 channels; h is bf16
__global__ __launch_bounds__(256) void rgcn_scatter(
    const int* __restrict__ esrc, const int* __restrict__ edst,
    const int* __restrict__ etype, int E, int filter, long hrel,
    const float* __restrict__ counts, const bf16* __restrict__ h,
    float* __restrict__ agg)
{
    const long gt = (long)blockIdx.x * 256 + threadIdx.x;
    const int  w  = (int)(gt >> 6);
    if (w >= E) return;
    const int t = etype[w];
    if (filter >= 0 && t != filter) return;
    const int lane = threadIdx.x & 63;
    const int s = esrc[w], d = edst[w];
    const float norm = 1.0f / fmaxf(counts[(long)d * NREL + t], 1.0f);
    const bf16* hp = h + (filter >= 0 ? 0L : (long)t * hrel) +
                     (long)s * 128 + (lane << 1);
    const ushort2 raw = *(const ushort2*)hp;
    const float vx = __uint_as_float((unsigned)raw.x << 16);
    const float vy = __uint_as_float((unsigned)raw.y << 16);
    float* ap = agg + (long)d * 128 + (lane << 1);
    atomicAdd(ap,     vx * norm);
    atomicAdd(ap + 1, vy * norm);
}

__global__ __launch_bounds__(256) void cvt_f32_bf16(
    const float* __restrict__ x, bf16* __restrict__ y, long n8)
{
    const long i = (long)blockIdx.x * 256 + threadIdx.x;
    if (i >= n8) return;
    const float4 a = *(const float4*)(x + i * 8);
    const float4 b = *(const float4*)(x + i * 8 + 4);
    bf16 o[8];
    o[0] = __float2bfloat16(a.x); o[1] = __float2bfloat16(a.y);
    o[2] = __float2bfloat16(a.z); o[3] = __float2bfloat16(a.w);
    o[4] = __float2bfloat16(b.x); o[5] = __float2bfloat16(b.y);
    o[6] = __float2bfloat16(b.z); o[7] = __float2bfloat16(b.w);
    *(s16x8*)(y + i * 8) = *(const s16x8*)o;
}

// w [R][K][128] f32 -> wT [R][128][K] bf16
__global__ __launch_bounds__(256) void cvt_w_transpose(
    const float* __restrict__ w, bf16* __restrict__ wt, int K, long total)
{
    const long idx = (long)blockIdx.x * 256 + threadIdx.x;
    if (idx >= total) return;
    const int  k  = (int)(idx % K);
    const long rn = idx / K;
    const int  n  = (int)(rn & 127);
    const long r  = rn >> 7;
    wt[idx] = __float2bfloat16(w[(r * K + k) * 128 + n]);
}

__global__ __launch_bounds__(256) void rgcn_copy_feat(
    const float* __restrict__ f, float* __restrict__ out, int N)
{
    const int idx   = blockIdx.x * blockDim.x + threadIdx.x;
    const int total = N * (IN_DIM / 4);
    if (idx >= total) return;
    const int n  = idx / (IN_DIM / 4);
    const int k4 = (idx % (IN_DIM / 4)) << 2;
    *(float4*)&out[(long)n * (IN_DIM + 128) + k4] =
        *(const float4*)&f[(long)n * IN_DIM + k4];
}

// ------------------------------------------------------------- launch ----
extern "C" void kernel_launch(void* const* d_in, const int* in_sizes, int n_in,
                              void* d_out, int out_size, void* d_ws,
                              size_t ws_size, hipStream_t stream)
{
    const float* feature = (const float*)d_in[0];
    const int*   eidx    = (const int*)d_in[1];
    const int*   etype   = (const int*)d_in[2];
    const float* w1      = (const float*)d_in[3];
    const float* root1   = (const float*)d_in[4];
    const float* b1      = (const float*)d_in[5];
    const float* w2      = (const float*)d_in[6];
    const float* root2   = (const float*)d_in[7];
    const float* b2      = (const float*)d_in[8];

    const int N = in_sizes[0] / IN_DIM;   // 50000
    const int E = in_sizes[2];            // 800000
    const int* esrc = eidx;
    const int* edst = eidx + E;
    const int NMT  = (N + 127) / 128;     // 391
    const int NP   = NMT * 128;           // 50048 (padded rows)

    char* p = (char*)d_ws;
    auto carve = [&](size_t b) { char* q = p; p += (b + 255) & ~(size_t)255; return q; };
    float* counts = (float*)carve((size_t)N * NREL * 4);
    float* agg    = (float*)carve((size_t)NP * 128 * 4);
    bf16*  x1b    = (bf16*)carve((size_t)NP * 128 * 2);
    bf16*  fb     = (bf16*)carve((size_t)NP * IN_DIM * 2);
    bf16*  w1T    = (bf16*)carve((size_t)NREL * 128 * IN_DIM * 2);
    bf16*  w2T    = (bf16*)carve((size_t)NREL * 128 * 128 * 2);
    bf16*  r1T    = (bf16*)carve((size_t)128 * IN_DIM * 2);
    bf16*  r2T    = (bf16*)carve((size_t)128 * 128 * 2);
    const size_t used_base = (size_t)(p - (char*)d_ws);
    const size_t h_full    = (size_t)NREL * NP * 128 * 2;
    const bool   full      = ws_size >= used_base + h_full;
    bf16* h = (bf16*)carve(full ? h_full : (size_t)NP * 128 * 2);
    const long hrel = (long)NP * 128;

    const int scat_blks  = (int)(((long)E * 64 + 255) / 256);
    const int count_blks = (E + 255) / 256;
    const int copy_blks  = (N * (IN_DIM / 4) + 255) / 256;

    // conversions
    {
        const long n8 = (long)N * IN_DIM / 8;
        cvt_f32_bf16<<<(int)((n8 + 255) / 256), 256, 0, stream>>>(feature, fb, n8);
        long t1 = (long)NREL * 128 * IN_DIM;
        cvt_w_transpose<<<(int)((t1 + 255) / 256), 256, 0, stream>>>(w1, w1T, IN_DIM, t1);
        long t2 = (long)NREL * 128 * 128;
        cvt_w_transpose<<<(int)((t2 + 255) / 256), 256, 0, stream>>>(w2, w2T, 128, t2);
        long t3 = (long)128 * IN_DIM;
        cvt_w_transpose<<<(int)((t3 + 255) / 256), 256, 0, stream>>>(root1, r1T, IN_DIM, t3);
        long t4 = (long)128 * 128;
        cvt_w_transpose<<<(int)((t4 + 255) / 256), 256, 0, stream>>>(root2, r2T, 128, t4);
    }

    hipMemsetAsync(counts, 0, (size_t)N * NREL * 4, stream);
    rgcn_count<<<count_blks, 256, 0, stream>>>(edst, etype, E, counts);

    // ---------------- layer 1 ----------------
    hipMemsetAsync(agg, 0, (size_t)NP * 128 * 4, stream);
    if (full) {
        mfma_gemm<false, false, false, bf16><<<NMT * NREL, 256, 0, stream>>>(
            fb, IN_DIM, w1T, (long)128 * IN_DIM, nullptr, nullptr,
            h, hrel, 128, 0, N, IN_DIM, NMT, NREL);
        rgcn_scatter<<<scat_blks, 256, 0, stream>>>(
            esrc, edst, etype, E, -1, hrel, counts, h, agg);
    } else {
        for (int r = 0; r < NREL; ++r) {
            mfma_gemm<false, false, false, bf16><<<NMT, 256, 0, stream>>>(
                fb, IN_DIM, w1T + (long)r * 128 * IN_DIM, 0, nullptr, nullptr,
                h, 0, 128, 0, N, IN_DIM, NMT, 0);
            rgcn_scatter<<<scat_blks, 256, 0, stream>>>(
                esrc, edst, etype, E, r, 0, counts, h, agg);
        }
    }
    // x1 = relu(agg + f @ root1 + b1)  (bf16 out, padded rows unguarded)
    mfma_gemm<true, true, false, bf16><<<NMT, 256, 0, stream>>>(
        fb, IN_DIM, r1T, 0, agg, b1, x1b, 0, 128, 0, N, IN_DIM, NMT, 0);

    // ---------------- layer 2 ----------------
    hipMemsetAsync(agg, 0, (size_t)NP * 128 * 4, stream);
    if (full) {
        mfma_gemm<false, false, false, bf16><<<NMT * NREL, 256, 0, stream>>>(
            x1b, 128, w2T, (long)128 * 128, nullptr, nullptr,
            h, hrel, 128, 0, N, 128, NMT, NREL);
        rgcn_scatter<<<scat_blks, 256, 0, stream>>>(
            esrc, edst, etype, E, -1, hrel, counts, h, agg);
    } else {
        for (int r = 0; r < NREL; ++r) {
            mfma_gemm<false, false, false, bf16><<<NMT, 256, 0, stream>>>(
                x1b, 128, w2T + (long)r * 128 * 128, 0, nullptr, nullptr,
                h, 0, 128, 0, N, 128, NMT, 0);
            rgcn_scatter<<<scat_blks, 256, 0, stream>>>(
                esrc, edst, etype, E, r, 0, counts, h, agg);
        }
    }
    // out[:, 768:896] = agg + x1 @ root2 + b2  (f32, guarded)
    mfma_gemm<false, true, true, float><<<NMT, 256, 0, stream>>>(
        x1b, 128, r2T, 0, agg, b2, (float*)d_out, 0, IN_DIM + 128, IN_DIM,
        N, 128, NMT, 0);
    // out[:, 0:768] = feature
    rgcn_copy_feat<<<copy_blks, 256, 0, stream>>>(feature, (float*)d_out, N);
}

// Round 3
// 506.158 us; speedup vs baseline: 5.4413x; 3.2737x over previous
//
#include <hip/hip_runtime.h>
#include <hip/hip_bf16.h>

// ---------------------------------------------------------------------------
// RGCN 2-layer forward, MI355X. Round 2: bf16 MFMA GEMMs + CSR-gather
// aggregation (no fp32 atomics). N=50000, E=800000, IN=768, HID=OUT=128, R=8.
// ---------------------------------------------------------------------------

typedef __hip_bfloat16 bf16;
typedef __attribute__((ext_vector_type(4))) float f32x4;
typedef __attribute__((ext_vector_type(8))) short s16x8;

#define IN_DIM 768
#define NREL   8

__device__ __forceinline__ void gload16(const void* g, void* l) {
    __builtin_amdgcn_global_load_lds(
        (const __attribute__((address_space(1))) void*)g,
        (__attribute__((address_space(3))) void*)l, 16, 0, 0);
}

// C = A[M,K](bf16) @ BT[128,K]^T(bf16) (+agg+bias)(relu) -> OutT
template <bool RELU, bool AGGBIAS, bool GUARD, typename OutT>
__global__ __launch_bounds__(256) void mfma_gemm(
    const bf16* __restrict__ A, int lda,
    const bf16* __restrict__ BT, long brel,
    const float* __restrict__ agg, const float* __restrict__ bias,
    OutT* __restrict__ C, long crel, int ldc, int coff,
    int M, int K, int nmt, int swz_nrel)
{
    __shared__ bf16 Asm[128 * 64];
    __shared__ bf16 Bsm[128 * 64];

    const int tid  = threadIdx.x;
    const int lane = tid & 63;
    const int wrow = ((tid >> 7) & 1) * 64;
    const int wcol = ((tid >> 6) & 1) * 64;

    int mtile, rel;
    if (swz_nrel == 0) {
        mtile = blockIdx.x; rel = 0;
    } else {
        const int id  = blockIdx.x;
        const int tot = nmt * swz_nrel;
        const int per = tot >> 3;
        const int w   = (id & 7) * per + (id >> 3);
        rel   = w % swz_nrel;
        mtile = w / swz_nrel;
    }
    const long m0 = (long)mtile * 128;
    const bf16* Bp = BT + (long)rel * brel;

    f32x4 acc[4][4];
#pragma unroll
    for (int i = 0; i < 4; ++i)
#pragma unroll
        for (int j = 0; j < 4; ++j) acc[i][j] = (f32x4){0.f, 0.f, 0.f, 0.f};

    for (int k0 = 0; k0 < K; k0 += 64) {
#pragma unroll
        for (int i = 0; i < 4; ++i) {
            const int flat = i * 256 + tid;
            const int row  = flat >> 3;
            const int sch  = (flat & 7) ^ (row & 7);
            char* ldsA = (char*)Asm + (i * 256 + (tid & 192)) * 16;
            char* ldsB = (char*)Bsm + (i * 256 + (tid & 192)) * 16;
            gload16(A  + (m0 + row) * (long)lda + k0 + sch * 8, ldsA);
            gload16(Bp + (long)row * K          + k0 + sch * 8, ldsB);
        }
        __syncthreads();

#pragma unroll
        for (int ks = 0; ks < 2; ++ks) {
            s16x8 af[4], bfr[4];
            const int g = ks * 4 + (lane >> 4);
#pragma unroll
            for (int i = 0; i < 4; ++i) {
                const int ar = wrow + i * 16 + (lane & 15);
                af[i] = *(const s16x8*)((const char*)Asm + ar * 128 +
                                        (g ^ (ar & 7)) * 16);
                const int br = wcol + i * 16 + (lane & 15);
                bfr[i] = *(const s16x8*)((const char*)Bsm + br * 128 +
                                         (g ^ (br & 7)) * 16);
            }
#pragma unroll
            for (int i = 0; i < 4; ++i)
#pragma unroll
                for (int j = 0; j < 4; ++j)
                    acc[i][j] = __builtin_amdgcn_mfma_f32_16x16x32_bf16(
                        af[i], bfr[j], acc[i][j], 0, 0, 0);
        }
        __syncthreads();
    }

    float breg[4];
    if (AGGBIAS) {
#pragma unroll
        for (int j = 0; j < 4; ++j) breg[j] = bias[wcol + j * 16 + (lane & 15)];
    }
    OutT* Cp = C + (long)rel * crel;
#pragma unroll
    for (int i = 0; i < 4; ++i) {
#pragma unroll
        for (int r = 0; r < 4; ++r) {
            const long row = m0 + wrow + i * 16 + (lane >> 4) * 4 + r;
            if (GUARD && row >= M) continue;
#pragma unroll
            for (int j = 0; j < 4; ++j) {
                float v = acc[i][j][r];
                const int col = wcol + j * 16 + (lane & 15);
                if (AGGBIAS) v += agg[row * 128 + col] + breg[j];
                if (RELU) v = fmaxf(v, 0.f);
                if constexpr (sizeof(OutT) == 2)
                    Cp[row * (long)ldc + coff + col] = __float2bfloat16(v);
                else
                    Cp[row * (long)ldc + coff + col] = v;
            }
        }
    }
}

// ------------------------------------------------------------- counts ----
__global__ __launch_bounds__(256) void rgcn_count(
    const int* __restrict__ edst, const int* __restrict__ etype, int E,
    float* __restrict__ counts)
{
    const int e = blockIdx.x * blockDim.x + threadIdx.x;
    if (e < E) atomicAdd(&counts[(long)edst[e] * NREL + etype[e]], 1.0f);
}

// ------------------------------------------------------------ CSR build ---
__global__ __launch_bounds__(256) void deg_block_scan(
    const float* __restrict__ counts, int N, int* __restrict__ rowstart,
    int* __restrict__ partials)
{
    __shared__ int s[256];
    const int d = blockIdx.x * 256 + threadIdx.x;
    int deg = 0;
    if (d < N) {
#pragma unroll
        for (int t = 0; t < NREL; ++t) deg += (int)counts[(long)d * NREL + t];
    }
    s[threadIdx.x] = deg;
    __syncthreads();
    for (int off = 1; off < 256; off <<= 1) {
        int v = (threadIdx.x >= off) ? s[threadIdx.x - off] : 0;
        __syncthreads();
        s[threadIdx.x] += v;
        __syncthreads();
    }
    if (d < N) rowstart[d] = s[threadIdx.x] - deg;  // block-local exclusive
    if (threadIdx.x == 255) partials[blockIdx.x] = s[255];
}

__global__ __launch_bounds__(256) void scan_partials(int* partials, int nb)
{
    __shared__ int s[256];
    const int v = (threadIdx.x < nb) ? partials[threadIdx.x] : 0;
    s[threadIdx.x] = v;
    __syncthreads();
    for (int off = 1; off < 256; off <<= 1) {
        int u = (threadIdx.x >= off) ? s[threadIdx.x - off] : 0;
        __syncthreads();
        s[threadIdx.x] += u;
        __syncthreads();
    }
    if (threadIdx.x < nb) partials[threadIdx.x] = s[threadIdx.x] - v;  // excl
}

__global__ __launch_bounds__(256) void add_base(
    int* __restrict__ rowstart, const int* __restrict__ partials, int N, int E)
{
    const int d = blockIdx.x * 256 + threadIdx.x;
    if (d < N) rowstart[d] += partials[blockIdx.x];
    if (d == 0) rowstart[N] = E;
}

__global__ __launch_bounds__(256) void csr_fill(
    const int* __restrict__ esrc, const int* __restrict__ edst,
    const int* __restrict__ etype, int E, const int* __restrict__ rowstart,
    int* __restrict__ cursor, int* __restrict__ epack)
{
    const int e = blockIdx.x * 256 + threadIdx.x;
    if (e >= E) return;
    const int d = edst[e];
    const int pos = atomicAdd(&cursor[d], 1);
    epack[rowstart[d] + pos] = esrc[e] | (etype[e] << 24);
}

// ------------------------------------------------------------- gather ----
// one wave per dst row; lane handles 2 channels. No atomics.
__global__ __launch_bounds__(256) void rgcn_gather(
    const int* __restrict__ rowstart, const int* __restrict__ epack,
    const float* __restrict__ counts, const bf16* __restrict__ h, long hrel,
    float* __restrict__ agg, int N, int NP)
{
    const int wid  = (blockIdx.x * 256 + threadIdx.x) >> 6;
    const int lane = threadIdx.x & 63;
    if (wid >= NP) return;
    float accx = 0.f, accy = 0.f;
    if (wid < N) {
        const int start = rowstart[wid];
        const int end   = rowstart[wid + 1];
        const float nrm =
            1.0f / fmaxf(counts[(long)wid * NREL + (lane & 7)], 1.0f);
        for (int base = start; base < end; base += 64) {
            const int rem = end - base;
            const int cnt = rem < 64 ? rem : 64;
            int w = 0;
            if (lane < rem) w = epack[base + lane];
            for (int i = 0; i < cnt; ++i) {
                const int word = __shfl(w, i);
                const int src  = word & 0xFFFFFF;
                const int t    = ((unsigned)word) >> 24;
                const float norm = __shfl(nrm, t);
                const ushort2 raw = *(const ushort2*)(
                    h + (long)t * hrel + (long)src * 128 + (lane << 1));
                accx += __uint_as_float((unsigned)raw.x << 16) * norm;
                accy += __uint_as_float((unsigned)raw.y << 16) * norm;
            }
        }
    }
    *(float2*)(agg + (long)wid * 128 + (lane << 1)) =
        make_float2(accx, accy);
}

// ---------------------------------------------------- fallback scatter ----
__global__ __launch_bounds__(256) void rgcn_scatter(
    const int* __restrict__ esrc, const int* __restrict__ edst,
    const int* __restrict__ etype, int E, int filter, long hrel,
    const float* __restrict__ counts, const bf16* __restrict__ h,
    float* __restrict__ agg)
{
    const long gt = (long)blockIdx.x * 256 + threadIdx.x;
    const int  w  = (int)(gt >> 6);
    if (w >= E) return;
    const int t = etype[w];
    if (filter >= 0 && t != filter) return;
    const int lane = threadIdx.x & 63;
    const int s = esrc[w], d = edst[w];
    const float norm = 1.0f / fmaxf(counts[(long)d * NREL + t], 1.0f);
    const bf16* hp = h + (filter >= 0 ? 0L : (long)t * hrel) +
                     (long)s * 128 + (lane << 1);
    const ushort2 raw = *(const ushort2*)hp;
    float* ap = agg + (long)d * 128 + (lane << 1);
    atomicAdd(ap,     __uint_as_float((unsigned)raw.x << 16) * norm);
    atomicAdd(ap + 1, __uint_as_float((unsigned)raw.y << 16) * norm);
}

// ------------------------------------------------------------- convert ----
__global__ __launch_bounds__(256) void cvt_f32_bf16(
    const float* __restrict__ x, bf16* __restrict__ y, long n8)
{
    const long i = (long)blockIdx.x * 256 + threadIdx.x;
    if (i >= n8) return;
    const float4 a = *(const float4*)(x + i * 8);
    const float4 b = *(const float4*)(x + i * 8 + 4);
    bf16 o[8];
    o[0] = __float2bfloat16(a.x); o[1] = __float2bfloat16(a.y);
    o[2] = __float2bfloat16(a.z); o[3] = __float2bfloat16(a.w);
    o[4] = __float2bfloat16(b.x); o[5] = __float2bfloat16(b.y);
    o[6] = __float2bfloat16(b.z); o[7] = __float2bfloat16(b.w);
    *(s16x8*)(y + i * 8) = *(const s16x8*)o;
}

__global__ __launch_bounds__(256) void cvt_w_transpose(
    const float* __restrict__ w, bf16* __restrict__ wt, int K, long total)
{
    const long idx = (long)blockIdx.x * 256 + threadIdx.x;
    if (idx >= total) return;
    const int  k  = (int)(idx % K);
    const long rn = idx / K;
    const int  n  = (int)(rn & 127);
    const long r  = rn >> 7;
    wt[idx] = __float2bfloat16(w[(r * K + k) * 128 + n]);
}

__global__ __launch_bounds__(256) void rgcn_copy_feat(
    const float* __restrict__ f, float* __restrict__ out, int N)
{
    const int idx   = blockIdx.x * blockDim.x + threadIdx.x;
    const int total = N * (IN_DIM / 4);
    if (idx >= total) return;
    const int n  = idx / (IN_DIM / 4);
    const int k4 = (idx % (IN_DIM / 4)) << 2;
    *(float4*)&out[(long)n * (IN_DIM + 128) + k4] =
        *(const float4*)&f[(long)n * IN_DIM + k4];
}

// ------------------------------------------------------------- launch ----
extern "C" void kernel_launch(void* const* d_in, const int* in_sizes, int n_in,
                              void* d_out, int out_size, void* d_ws,
                              size_t ws_size, hipStream_t stream)
{
    const float* feature = (const float*)d_in[0];
    const int*   eidx    = (const int*)d_in[1];
    const int*   etype   = (const int*)d_in[2];
    const float* w1      = (const float*)d_in[3];
    const float* root1   = (const float*)d_in[4];
    const float* b1      = (const float*)d_in[5];
    const float* w2      = (const float*)d_in[6];
    const float* root2   = (const float*)d_in[7];
    const float* b2      = (const float*)d_in[8];

    const int N = in_sizes[0] / IN_DIM;   // 50000
    const int E = in_sizes[2];            // 800000
    const int* esrc = eidx;
    const int* edst = eidx + E;
    const int NMT = (N + 127) / 128;      // 391
    const int NP  = NMT * 128;            // 50048

    char* p = (char*)d_ws;
    auto carve = [&](size_t b) { char* q = p; p += (b + 255) & ~(size_t)255; return q; };
    float* counts   = (float*)carve((size_t)N * NREL * 4);
    float* agg      = (float*)carve((size_t)NP * 128 * 4);
    bf16*  x1b      = (bf16*)carve((size_t)NP * 128 * 2);
    bf16*  fb       = (bf16*)carve((size_t)NP * IN_DIM * 2);
    bf16*  w1T      = (bf16*)carve((size_t)NREL * 128 * IN_DIM * 2);
    bf16*  w2T      = (bf16*)carve((size_t)NREL * 128 * 128 * 2);
    bf16*  r1T      = (bf16*)carve((size_t)128 * IN_DIM * 2);
    bf16*  r2T      = (bf16*)carve((size_t)128 * 128 * 2);
    int*   rowstart = (int*)carve((size_t)(N + 1) * 4);
    int*   cursor   = (int*)carve((size_t)N * 4);
    int*   partials = (int*)carve(1024);
    int*   epack    = (int*)carve((size_t)E * 4);
    const size_t used_base = (size_t)(p - (char*)d_ws);
    const size_t h_full    = (size_t)NREL * NP * 128 * 2;
    const bool   full      = ws_size >= used_base + h_full;
    bf16* h = (bf16*)carve(full ? h_full : (size_t)NP * 128 * 2);
    const long hrel = (long)NP * 128;

    const int count_blks = (E + 255) / 256;
    const int copy_blks  = (N * (IN_DIM / 4) + 255) / 256;
    const int nblk       = (N + 255) / 256;           // 196
    const int gat_blks   = (NP * 64) / 256;
    const int scat_blks  = (int)(((long)E * 64 + 255) / 256);

    // conversions
    {
        const long n8 = (long)N * IN_DIM / 8;
        cvt_f32_bf16<<<(int)((n8 + 255) / 256), 256, 0, stream>>>(feature, fb, n8);
        long t1 = (long)NREL * 128 * IN_DIM;
        cvt_w_transpose<<<(int)((t1 + 255) / 256), 256, 0, stream>>>(w1, w1T, IN_DIM, t1);
        long t2 = (long)NREL * 128 * 128;
        cvt_w_transpose<<<(int)((t2 + 255) / 256), 256, 0, stream>>>(w2, w2T, 128, t2);
        long t3 = (long)128 * IN_DIM;
        cvt_w_transpose<<<(int)((t3 + 255) / 256), 256, 0, stream>>>(root1, r1T, IN_DIM, t3);
        long t4 = (long)128 * 128;
        cvt_w_transpose<<<(int)((t4 + 255) / 256), 256, 0, stream>>>(root2, r2T, 128, t4);
    }

    // counts + CSR (shared by both layers)
    hipMemsetAsync(counts, 0, (size_t)N * NREL * 4, stream);
    rgcn_count<<<count_blks, 256, 0, stream>>>(edst, etype, E, counts);
    if (full) {
        deg_block_scan<<<nblk, 256, 0, stream>>>(counts, N, rowstart, partials);
        scan_partials<<<1, 256, 0, stream>>>(partials, nblk);
        add_base<<<nblk, 256, 0, stream>>>(rowstart, partials, N, E);
        hipMemsetAsync(cursor, 0, (size_t)N * 4, stream);
        csr_fill<<<count_blks, 256, 0, stream>>>(esrc, edst, etype, E,
                                                 rowstart, cursor, epack);
    }

    // ---------------- layer 1 ----------------
    if (full) {
        mfma_gemm<false, false, false, bf16><<<NMT * NREL, 256, 0, stream>>>(
            fb, IN_DIM, w1T, (long)128 * IN_DIM, nullptr, nullptr,
            h, hrel, 128, 0, N, IN_DIM, NMT, NREL);
        rgcn_gather<<<gat_blks, 256, 0, stream>>>(
            rowstart, epack, counts, h, hrel, agg, N, NP);
    } else {
        hipMemsetAsync(agg, 0, (size_t)NP * 128 * 4, stream);
        for (int r = 0; r < NREL; ++r) {
            mfma_gemm<false, false, false, bf16><<<NMT, 256, 0, stream>>>(
                fb, IN_DIM, w1T + (long)r * 128 * IN_DIM, 0, nullptr, nullptr,
                h, 0, 128, 0, N, IN_DIM, NMT, 0);
            rgcn_scatter<<<scat_blks, 256, 0, stream>>>(
                esrc, edst, etype, E, r, 0, counts, h, agg);
        }
    }
    mfma_gemm<true, true, false, bf16><<<NMT, 256, 0, stream>>>(
        fb, IN_DIM, r1T, 0, agg, b1, x1b, 0, 128, 0, N, IN_DIM, NMT, 0);

    // ---------------- layer 2 ----------------
    if (full) {
        mfma_gemm<false, false, false, bf16><<<NMT * NREL, 256, 0, stream>>>(
            x1b, 128, w2T, (long)128 * 128, nullptr, nullptr,
            h, hrel, 128, 0, N, 128, NMT, NREL);
        rgcn_gather<<<gat_blks, 256, 0, stream>>>(
            rowstart, epack, counts, h, hrel, agg, N, NP);
    } else {
        hipMemsetAsync(agg, 0, (size_t)NP * 128 * 4, stream);
        for (int r = 0; r < NREL; ++r) {
            mfma_gemm<false, false, false, bf16><<<NMT, 256, 0, stream>>>(
                x1b, 128, w2T + (long)r * 128 * 128, 0, nullptr, nullptr,
                h, 0, 128, 0, N, 128, NMT, 0);
            rgcn_scatter<<<scat_blks, 256, 0, stream>>>(
                esrc, edst, etype, E, r, 0, counts, h, agg);
        }
    }
    mfma_gemm<false, true, true, float><<<NMT, 256, 0, stream>>>(
        x1b, 128, r2T, 0, agg, b2, (float*)d_out, 0, IN_DIM + 128, IN_DIM,
        N, 128, NMT, 0);
    rgcn_copy_feat<<<copy_blks, 256, 0, stream>>>(feature, (float*)d_out, N);
}

// Round 4
// 436.934 us; speedup vs baseline: 6.3034x; 1.1584x over previous
//
#include <hip/hip_runtime.h>
#include <hip/hip_bf16.h>

// ---------------------------------------------------------------------------
// RGCN 2-layer forward, MI355X. Round 3: root-fused merged GEMM (N=9*128),
// CSR gather (2 edges/iter), bf16 agg, fused cvt+feature-copy.
// N=50000, E=800000, IN=768, HID=OUT=128, R=8.
// ---------------------------------------------------------------------------

typedef __hip_bfloat16 bf16;
typedef __attribute__((ext_vector_type(4))) float f32x4;
typedef __attribute__((ext_vector_type(8))) short s16x8;

#define IN_DIM 768
#define NREL   8
#define NTL    9          // 8 relations + root
#define LDH    (NTL*128)  // 1152

__device__ __forceinline__ float bf2f(unsigned short u) {
    return __uint_as_float((unsigned)u << 16);
}
__device__ __forceinline__ unsigned short f2bf(float f) {
    __hip_bfloat16 b = __float2bfloat16(f);
    return *(unsigned short*)&b;
}

__device__ __forceinline__ void gload16(const void* g, void* l) {
    __builtin_amdgcn_global_load_lds(
        (const __attribute__((address_space(1))) void*)g,
        (__attribute__((address_space(3))) void*)l, 16, 0, 0);
}

// C[m, ntile*128+c] = A[M,K](bf16) @ BT[ntl*128, K]^T -> bf16
__global__ __launch_bounds__(256) void mfma_gemm(
    const bf16* __restrict__ A, int lda, const bf16* __restrict__ BT,
    bf16* __restrict__ C, int K, int nmt, int ntl)
{
    __shared__ bf16 Asm[128 * 64];
    __shared__ bf16 Bsm[128 * 64];

    const int tid  = threadIdx.x;
    const int lane = tid & 63;
    const int wrow = ((tid >> 7) & 1) * 64;
    const int wcol = ((tid >> 6) & 1) * 64;

    // bijective XCD-aware swizzle (m204): consecutive w share an mtile
    const int nwg  = nmt * ntl;
    const int orig = blockIdx.x;
    const int xcd  = orig & 7;
    const int q    = nwg >> 3, rr = nwg & 7;
    const int bse  = (xcd < rr) ? xcd * (q + 1) : rr * (q + 1) + (xcd - rr) * q;
    const int w    = bse + (orig >> 3);
    const int ntile = w % ntl;
    const int mtile = w / ntl;
    const long m0   = (long)mtile * 128;
    const bf16* Bp  = BT + (long)ntile * 128 * K;
    const int  ldh  = ntl * 128;
    const int  ncol0 = ntile * 128;

    f32x4 acc[4][4];
#pragma unroll
    for (int i = 0; i < 4; ++i)
#pragma unroll
        for (int j = 0; j < 4; ++j) acc[i][j] = (f32x4){0.f, 0.f, 0.f, 0.f};

    for (int k0 = 0; k0 < K; k0 += 64) {
#pragma unroll
        for (int i = 0; i < 4; ++i) {
            const int flat = i * 256 + tid;
            const int row  = flat >> 3;
            const int sch  = (flat & 7) ^ (row & 7);
            char* ldsA = (char*)Asm + (i * 256 + (tid & 192)) * 16;
            char* ldsB = (char*)Bsm + (i * 256 + (tid & 192)) * 16;
            gload16(A  + (m0 + row) * (long)lda + k0 + sch * 8, ldsA);
            gload16(Bp + (long)row * K          + k0 + sch * 8, ldsB);
        }
        __syncthreads();

#pragma unroll
        for (int ks = 0; ks < 2; ++ks) {
            s16x8 af[4], bfr[4];
            const int g = ks * 4 + (lane >> 4);
#pragma unroll
            for (int i = 0; i < 4; ++i) {
                const int ar = wrow + i * 16 + (lane & 15);
                af[i] = *(const s16x8*)((const char*)Asm + ar * 128 +
                                        (g ^ (ar & 7)) * 16);
                const int br = wcol + i * 16 + (lane & 15);
                bfr[i] = *(const s16x8*)((const char*)Bsm + br * 128 +
                                         (g ^ (br & 7)) * 16);
            }
#pragma unroll
            for (int i = 0; i < 4; ++i)
#pragma unroll
                for (int j = 0; j < 4; ++j)
                    acc[i][j] = __builtin_amdgcn_mfma_f32_16x16x32_bf16(
                        af[i], bfr[j], acc[i][j], 0, 0, 0);
        }
        __syncthreads();
    }

    // C/D layout: col=lane&15, row=(lane>>4)*4+reg (m89-verified)
#pragma unroll
    for (int i = 0; i < 4; ++i) {
#pragma unroll
        for (int r = 0; r < 4; ++r) {
            const long row = m0 + wrow + i * 16 + (lane >> 4) * 4 + r;
#pragma unroll
            for (int j = 0; j < 4; ++j) {
                const int col = wcol + j * 16 + (lane & 15);
                C[row * (long)ldh + ncol0 + col] =
                    __float2bfloat16(acc[i][j][r]);
            }
        }
    }
}

// ------------------------------------------------------------- counts ----
__global__ __launch_bounds__(256) void rgcn_count(
    const int* __restrict__ edst, const int* __restrict__ etype, int E,
    float* __restrict__ counts)
{
    const int e = blockIdx.x * blockDim.x + threadIdx.x;
    if (e < E) atomicAdd(&counts[(long)edst[e] * NREL + etype[e]], 1.0f);
}

// ------------------------------------------------------------ CSR build ---
__global__ __launch_bounds__(256) void deg_block_scan(
    const float* __restrict__ counts, int N, int* __restrict__ rowstart,
    int* __restrict__ partials)
{
    __shared__ int s[256];
    const int d = blockIdx.x * 256 + threadIdx.x;
    int deg = 0;
    if (d < N) {
#pragma unroll
        for (int t = 0; t < NREL; ++t) deg += (int)counts[(long)d * NREL + t];
    }
    s[threadIdx.x] = deg;
    __syncthreads();
    for (int off = 1; off < 256; off <<= 1) {
        int v = (threadIdx.x >= off) ? s[threadIdx.x - off] : 0;
        __syncthreads();
        s[threadIdx.x] += v;
        __syncthreads();
    }
    if (d < N) rowstart[d] = s[threadIdx.x] - deg;
    if (threadIdx.x == 255) partials[blockIdx.x] = s[255];
}

__global__ __launch_bounds__(256) void scan_partials(int* partials, int nb)
{
    __shared__ int s[256];
    const int v = (threadIdx.x < nb) ? partials[threadIdx.x] : 0;
    s[threadIdx.x] = v;
    __syncthreads();
    for (int off = 1; off < 256; off <<= 1) {
        int u = (threadIdx.x >= off) ? s[threadIdx.x - off] : 0;
        __syncthreads();
        s[threadIdx.x] += u;
        __syncthreads();
    }
    if (threadIdx.x < nb) partials[threadIdx.x] = s[threadIdx.x] - v;
}

__global__ __launch_bounds__(256) void add_base(
    int* __restrict__ rowstart, const int* __restrict__ partials, int N, int E)
{
    const int d = blockIdx.x * 256 + threadIdx.x;
    if (d < N) rowstart[d] += partials[blockIdx.x];
    if (d == 0) rowstart[N] = E;
}

__global__ __launch_bounds__(256) void csr_fill(
    const int* __restrict__ esrc, const int* __restrict__ edst,
    const int* __restrict__ etype, int E, const int* __restrict__ rowstart,
    int* __restrict__ cursor, int* __restrict__ epack)
{
    const int e = blockIdx.x * 256 + threadIdx.x;
    if (e >= E) return;
    const int d = edst[e];
    const int pos = atomicAdd(&cursor[d], 1);
    epack[rowstart[d] + pos] = esrc[e] | (etype[e] << 24);
}

// ------------------------------------------------------------- gather ----
// one wave per dst row; 2 edges/iter (32 lanes x ushort4 per edge).
// agg output is bf16.
__global__ __launch_bounds__(256) void rgcn_gather(
    const int* __restrict__ rowstart, const int* __restrict__ epack,
    const float* __restrict__ counts, const bf16* __restrict__ h,
    bf16* __restrict__ agg, int N, int NP)
{
    const int wid  = (blockIdx.x * 256 + threadIdx.x) >> 6;
    if (wid >= NP) return;
    const int lane = threadIdx.x & 63;
    const int half = lane >> 5;
    const int l32  = lane & 31;
    float a0 = 0.f, a1 = 0.f, a2 = 0.f, a3 = 0.f;
    if (wid < N) {
        const int start = rowstart[wid];
        const int end   = rowstart[wid + 1];
        const float nrm =
            1.0f / fmaxf(counts[(long)wid * NREL + (lane & 7)], 1.0f);
        for (int base = start; base < end; base += 64) {
            const int rem = end - base;
            const int cnt = rem < 64 ? rem : 64;
            int wv = 0;
            if (lane < cnt) wv = epack[base + lane];
            for (int i = 0; i < cnt; i += 2) {
                const int  idx   = i + half;
                const bool valid = idx < cnt;
                const int  word  = __shfl(wv, idx);
                int src = 0, t = 0;
                if (valid) { src = word & 0xFFFFFF; t = ((unsigned)word) >> 24; }
                const float norm = __shfl(nrm, t);
                if (valid) {
                    const ushort4 raw = *(const ushort4*)(
                        h + (long)src * LDH + t * 128 + l32 * 4);
                    a0 += bf2f(raw.x) * norm;
                    a1 += bf2f(raw.y) * norm;
                    a2 += bf2f(raw.z) * norm;
                    a3 += bf2f(raw.w) * norm;
                }
            }
        }
    }
    // fold the two halves (same channels)
    a0 += __shfl(a0, lane ^ 32);
    a1 += __shfl(a1, lane ^ 32);
    a2 += __shfl(a2, lane ^ 32);
    a3 += __shfl(a3, lane ^ 32);
    if (half == 0) {
        ushort4 o;
        o.x = f2bf(a0); o.y = f2bf(a1); o.z = f2bf(a2); o.w = f2bf(a3);
        *(ushort4*)(agg + (long)wid * 128 + l32 * 4) = o;
    }
}

// ------------------------------------------------------- epilogues -------
// x1b = relu(h[:,1024:1152] + agg + b1)   (all NP rows)
__global__ __launch_bounds__(256) void epilogue1(
    const bf16* __restrict__ h, const bf16* __restrict__ agg,
    const float* __restrict__ b1, bf16* __restrict__ x1b, int NP)
{
    const int idx = blockIdx.x * 256 + threadIdx.x;
    if (idx >= NP * 16) return;
    const int n  = idx >> 4;
    const int c8 = (idx & 15) << 3;
    const s16x8 hv = *(const s16x8*)(h + (long)n * LDH + NREL * 128 + c8);
    const s16x8 av = *(const s16x8*)(agg + (long)n * 128 + c8);
    const float4 bA = *(const float4*)(b1 + c8);
    const float4 bB = *(const float4*)(b1 + c8 + 4);
    const float bb[8] = {bA.x, bA.y, bA.z, bA.w, bB.x, bB.y, bB.z, bB.w};
    bf16 o[8];
#pragma unroll
    for (int j = 0; j < 8; ++j) {
        float v = bf2f((unsigned short)hv[j]) +
                  bf2f((unsigned short)av[j]) + bb[j];
        o[j] = __float2bfloat16(fmaxf(v, 0.f));
    }
    *(s16x8*)(x1b + (long)n * 128 + c8) = *(const s16x8*)o;
}

// out[:,768:896] = h[:,1024:1152] + agg + b2   (rows < N, f32)
__global__ __launch_bounds__(256) void epilogue2(
    const bf16* __restrict__ h, const bf16* __restrict__ agg,
    const float* __restrict__ b2, float* __restrict__ out, int N)
{
    const int idx = blockIdx.x * 256 + threadIdx.x;
    if (idx >= N * 16) return;
    const int n  = idx >> 4;
    const int c8 = (idx & 15) << 3;
    const s16x8 hv = *(const s16x8*)(h + (long)n * LDH + NREL * 128 + c8);
    const s16x8 av = *(const s16x8*)(agg + (long)n * 128 + c8);
    const float4 bA = *(const float4*)(b2 + c8);
    const float4 bB = *(const float4*)(b2 + c8 + 4);
    const float bb[8] = {bA.x, bA.y, bA.z, bA.w, bB.x, bB.y, bB.z, bB.w};
    float v[8];
#pragma unroll
    for (int j = 0; j < 8; ++j)
        v[j] = bf2f((unsigned short)hv[j]) + bf2f((unsigned short)av[j]) + bb[j];
    float* op = out + (long)n * (IN_DIM + 128) + IN_DIM + c8;
    *(float4*)op       = make_float4(v[0], v[1], v[2], v[3]);
    *(float4*)(op + 4) = make_float4(v[4], v[5], v[6], v[7]);
}

// -------------------------------------------- fused cvt + feature copy ----
__global__ __launch_bounds__(256) void cvt_copy(
    const float* __restrict__ f, bf16* __restrict__ fb,
    float* __restrict__ out, int N)
{
    const int idx = blockIdx.x * 256 + threadIdx.x;
    if (idx >= N * (IN_DIM / 8)) return;
    const int n  = idx / (IN_DIM / 8);
    const int k8 = (idx % (IN_DIM / 8)) << 3;
    const float4 a = *(const float4*)(f + (long)n * IN_DIM + k8);
    const float4 b = *(const float4*)(f + (long)n * IN_DIM + k8 + 4);
    float* op = out + (long)n * (IN_DIM + 128) + k8;
    *(float4*)op       = a;
    *(float4*)(op + 4) = b;
    bf16 o[8];
    o[0] = __float2bfloat16(a.x); o[1] = __float2bfloat16(a.y);
    o[2] = __float2bfloat16(a.z); o[3] = __float2bfloat16(a.w);
    o[4] = __float2bfloat16(b.x); o[5] = __float2bfloat16(b.y);
    o[6] = __float2bfloat16(b.z); o[7] = __float2bfloat16(b.w);
    *(s16x8*)(fb + (long)n * IN_DIM + k8) = *(const s16x8*)o;
}

// w [R][K][128] f32 -> wt [R][128][K] bf16
__global__ __launch_bounds__(256) void cvt_w_transpose(
    const float* __restrict__ w, bf16* __restrict__ wt, int K, long total)
{
    const long idx = (long)blockIdx.x * 256 + threadIdx.x;
    if (idx >= total) return;
    const int  k  = (int)(idx % K);
    const long rn = idx / K;
    const int  n  = (int)(rn & 127);
    const long r  = rn >> 7;
    wt[idx] = __float2bfloat16(w[(r * K + k) * 128 + n]);
}

// ------------------------------------------------------------- launch ----
extern "C" void kernel_launch(void* const* d_in, const int* in_sizes, int n_in,
                              void* d_out, int out_size, void* d_ws,
                              size_t ws_size, hipStream_t stream)
{
    const float* feature = (const float*)d_in[0];
    const int*   eidx    = (const int*)d_in[1];
    const int*   etype   = (const int*)d_in[2];
    const float* w1      = (const float*)d_in[3];
    const float* root1   = (const float*)d_in[4];
    const float* b1      = (const float*)d_in[5];
    const float* w2      = (const float*)d_in[6];
    const float* root2   = (const float*)d_in[7];
    const float* b2      = (const float*)d_in[8];

    const int N = in_sizes[0] / IN_DIM;   // 50000
    const int E = in_sizes[2];            // 800000
    const int* esrc = eidx;
    const int* edst = eidx + E;
    const int NMT = (N + 127) / 128;      // 391
    const int NP  = NMT * 128;            // 50048

    char* p = (char*)d_ws;
    auto carve = [&](size_t b) { char* q = p; p += (b + 255) & ~(size_t)255; return q; };
    float* counts   = (float*)carve((size_t)N * NREL * 4);       // 1.6 MB
    bf16*  agg      = (bf16*)carve((size_t)NP * 128 * 2);        // 12.8 MB
    bf16*  x1b      = (bf16*)carve((size_t)NP * 128 * 2);        // 12.8 MB
    bf16*  fb       = (bf16*)carve((size_t)NP * IN_DIM * 2);     // 76.9 MB
    bf16*  w1m      = (bf16*)carve((size_t)NTL * 128 * IN_DIM * 2);
    bf16*  w2m      = (bf16*)carve((size_t)NTL * 128 * 128 * 2);
    int*   rowstart = (int*)carve((size_t)(N + 1) * 4);
    int*   cursor   = (int*)carve((size_t)N * 4);
    int*   partials = (int*)carve(1024);
    int*   epack    = (int*)carve((size_t)E * 4);                // 3.2 MB
    bf16*  h        = (bf16*)carve((size_t)NP * LDH * 2);        // 115.3 MB
    (void)ws_size;  // total 225.07 MB — proven available in R2

    const int count_blks = (E + 255) / 256;
    const int nblk       = (N + 255) / 256;
    const int gat_blks   = NP / 4;           // NP*64/256
    const int gemm_blks  = NMT * NTL;        // 3519

    // conversions (feature cvt fused with out[:, :768] copy)
    cvt_copy<<<(N * (IN_DIM / 8) + 255) / 256, 256, 0, stream>>>(
        feature, fb, (float*)d_out, N);
    {
        long t1 = (long)NREL * 128 * IN_DIM;
        cvt_w_transpose<<<(int)((t1 + 255) / 256), 256, 0, stream>>>(
            w1, w1m, IN_DIM, t1);
        long t1r = (long)128 * IN_DIM;
        cvt_w_transpose<<<(int)((t1r + 255) / 256), 256, 0, stream>>>(
            root1, w1m + (long)NREL * 128 * IN_DIM, IN_DIM, t1r);
        long t2 = (long)NREL * 128 * 128;
        cvt_w_transpose<<<(int)((t2 + 255) / 256), 256, 0, stream>>>(
            w2, w2m, 128, t2);
        long t2r = (long)128 * 128;
        cvt_w_transpose<<<(int)((t2r + 255) / 256), 256, 0, stream>>>(
            root2, w2m + (long)NREL * 128 * 128, 128, t2r);
    }

    // counts + CSR (shared by both layers)
    hipMemsetAsync(counts, 0, (size_t)N * NREL * 4, stream);
    rgcn_count<<<count_blks, 256, 0, stream>>>(edst, etype, E, counts);
    deg_block_scan<<<nblk, 256, 0, stream>>>(counts, N, rowstart, partials);
    scan_partials<<<1, 256, 0, stream>>>(partials, nblk);
    add_base<<<nblk, 256, 0, stream>>>(rowstart, partials, N, E);
    hipMemsetAsync(cursor, 0, (size_t)N * 4, stream);
    csr_fill<<<count_blks, 256, 0, stream>>>(esrc, edst, etype, E,
                                             rowstart, cursor, epack);

    // ---------------- layer 1 ----------------
    mfma_gemm<<<gemm_blks, 256, 0, stream>>>(fb, IN_DIM, w1m, h,
                                             IN_DIM, NMT, NTL);
    rgcn_gather<<<gat_blks, 256, 0, stream>>>(rowstart, epack, counts, h,
                                              agg, N, NP);
    epilogue1<<<NP / 16, 256, 0, stream>>>(h, agg, b1, x1b, NP);

    // ---------------- layer 2 ----------------
    mfma_gemm<<<gemm_blks, 256, 0, stream>>>(x1b, 128, w2m, h,
                                             128, NMT, NTL);
    rgcn_gather<<<gat_blks, 256, 0, stream>>>(rowstart, epack, counts, h,
                                              agg, N, NP);
    epilogue2<<<(N * 16 + 255) / 256, 256, 0, stream>>>(h, agg, b2,
                                                        (float*)d_out, N);
}